// Round 8
// baseline (637.583 us; speedup 1.0000x reference)
//
#include <hip/hip_runtime.h>
#include <cstdint>
#include <cstddef>

// Problem constants
#define BB 2
#define HB 16
#define LL 2048
#define DD 128
#define MM 4096   // B*L
#define KK 2048   // DIM
#define N1 6144   // 3*DIM
#define N2 2048   // DIM
#define BHLD (BB*HB*LL*DD)  // 8388608 elements per q/k/v section

typedef unsigned short u16;
typedef __bf16 bf16x8 __attribute__((ext_vector_type(8)));   // 4 VGPRs: mfma 16x16x32 A/B operand
typedef short  s16x4  __attribute__((ext_vector_type(4)));   // 2 VGPRs: mfma 16x16x16 (_1k) A/B operand
typedef float  f32x4  __attribute__((ext_vector_type(4)));

typedef __attribute__((address_space(1))) void* as1_ptr;
typedef __attribute__((address_space(3))) void* as3_ptr;

// async global->LDS, 16B per lane; LDS dest = wave-uniform base + lane*16 [m97/m104]
__device__ __forceinline__ void gload16(const void* g, void* l) {
  __builtin_amdgcn_global_load_lds((as1_ptr)g, (as3_ptr)l, 16, 0, 0);
}

__device__ __forceinline__ float bf2f(u16 u) {
  union { unsigned v; float f; } c; c.v = ((unsigned)u) << 16; return c.f;
}
__device__ __forceinline__ u16 f2bf(float f) {  // round-to-nearest-even
  unsigned u = __builtin_bit_cast(unsigned, f);
  return (u16)((u + 0x7FFFu + ((u >> 16) & 1u)) >> 16);
}

// ---------------- merged prep kernel ----------------
// blocks [0,8192): x fp32 -> bf16 cast (1024 elems/block)
// blocks [8192,20480): transpose+cast qkv_w [KK][N1] -> w1t [N1][KK]
// blocks [20480,24576): transpose+cast proj_w [KK][N2] -> w2t [N2][KK]
__global__ __launch_bounds__(256) void prep(
    const float* __restrict__ x,  u16* __restrict__ xb,
    const float* __restrict__ w1, u16* __restrict__ w1t,
    const float* __restrict__ w2, u16* __restrict__ w2t)
{
  __shared__ float t[32][33];
  const int bid = blockIdx.x;
  if (bid < 8192) {
    int i = bid * 256 + threadIdx.x;
    float4 v = ((const float4*)x)[i];
    ushort4 o;
    o.x = f2bf(v.x); o.y = f2bf(v.y); o.z = f2bf(v.z); o.w = f2bf(v.w);
    ((ushort4*)xb)[i] = o;
    return;
  }
  const float* in; u16* out; int C, idx;
  if (bid < 20480) { idx = bid - 8192;  in = w1; out = w1t; C = N1; }
  else             { idx = bid - 20480; in = w2; out = w2t; C = N2; }
  const int xt = C / 32;
  const int c0 = (idx % xt) * 32, r0 = (idx / xt) * 32;
  const int tx = threadIdx.x & 31, ty = threadIdx.x >> 5;  // 8 rows per pass
#pragma unroll
  for (int i = ty; i < 32; i += 8)
    t[i][tx] = in[(size_t)(r0 + i) * C + c0 + tx];
  __syncthreads();
#pragma unroll
  for (int i = ty; i < 32; i += 8)
    out[(size_t)(c0 + i) * KK + r0 + tx] = f2bf(t[tx][i]);
}

// ---------------- GEMM (A [M][K] bf16, Bt [N][K] bf16) ----------------
// m97 pattern + BK=64 + XOR chunk swizzle (round 5: 0 bank conflicts, ~760 TF).
// MODE 0: fused epilogue. Tile = 128 (b,l)-rows x one head's full d (n0 mult of 128):
//   q,k sections: bias -> fp32 RMSNorm over d (in-tile: shfl + LDS cross-wave) ->
//   RoPE (pair = adjacent lanes, shfl_xor(1)) -> scatter [B][H][L][D] bf16.
//   (q also pre-scaled by 1/sqrt(128)). v section: bias -> scatter [B][H][D][L].
// MODE 1: plain fp32 row-major store [M][N].
template<int MODE>
__global__ __launch_bounds__(256) void gemm_bt(
    const u16* __restrict__ A, const u16* __restrict__ Bt,
    const float* __restrict__ bias, void* __restrict__ Cout,
    const float* __restrict__ pe, const float* __restrict__ qsc,
    const float* __restrict__ ksc, int Msz, int Nsz, int Ksz)
{
  __shared__ __align__(16) u16 As[128*64];   // 16 KB
  __shared__ __align__(16) u16 Bs[128*64];   // 16 KB
  const int tid  = threadIdx.x;
  const int lane = tid & 63;
  const int wid  = tid >> 6;
  const int l15  = lane & 15, quad = lane >> 4;
  const int m0 = blockIdx.y * 128, n0 = blockIdx.x * 128;
  const int wm = (wid >> 1) * 64, wn = (wid & 1) * 64;

  f32x4 acc[4][4] = {};

  for (int ks = 0; ks < Ksz; ks += 64) {
    __syncthreads();
    // staging: 1024 16B-slots per tile; slot s -> row s>>3, chunk s&7 (swizzled)
#pragma unroll
    for (int j = 0; j < 4; j++) {
      const int s = (wid*4 + j)*64 + lane;
      const int row = s >> 3, pc = (s & 7) ^ (row & 7);
      gload16(&A [(size_t)(m0 + row) * Ksz + ks + pc*8], &As[(wid*4 + j)*512]);
      gload16(&Bt[(size_t)(n0 + row) * Ksz + ks + pc*8], &Bs[(wid*4 + j)*512]);
    }
    __syncthreads();
#pragma unroll
    for (int kh = 0; kh < 2; kh++) {
      bf16x8 af[4], bfr[4];
#pragma unroll
      for (int i = 0; i < 4; i++) {
        const int r = wm + i*16 + l15;
        af[i]  = *(const bf16x8*)&As[r*64 + (((kh*4 + quad) ^ (r & 7)))*8];
      }
#pragma unroll
      for (int i = 0; i < 4; i++) {
        const int r = wn + i*16 + l15;
        bfr[i] = *(const bf16x8*)&Bs[r*64 + (((kh*4 + quad) ^ (r & 7)))*8];
      }
#pragma unroll
      for (int i = 0; i < 4; i++)
#pragma unroll
        for (int j = 0; j < 4; j++)
          acc[i][j] = __builtin_amdgcn_mfma_f32_16x16x32_bf16(af[i], bfr[j], acc[i][j], 0, 0, 0);
    }
  }

  // C/D layout: row = quad*4+reg (m), col = lane&15 (n)  [verified m89/m91]
  if (MODE == 1) {
#pragma unroll
    for (int i = 0; i < 4; i++)
#pragma unroll
      for (int j = 0; j < 4; j++) {
        const int col = n0 + wn + j*16 + l15;
        const float bv = bias[col];
#pragma unroll
        for (int r = 0; r < 4; r++) {
          const int row = m0 + wm + i*16 + quad*4 + r;
          ((float*)Cout)[(size_t)row * Nsz + col] = acc[i][j][r] + bv;
        }
      }
    return;
  }

  // ---- MODE 0 fused epilogue ----
  u16* qkv = (u16*)Cout;
  const int t = n0 >> 11;            // 0=q 1=k 2=v (block-uniform)
  const int h = (n0 >> 7) & 15;
  float bv[4];
#pragma unroll
  for (int j = 0; j < 4; j++) bv[j] = bias[n0 + wn + j*16 + l15];

  if (t == 2) {  // v: bias + scatter [B][H][D][L]
#pragma unroll
    for (int i = 0; i < 4; i++)
#pragma unroll
      for (int j = 0; j < 4; j++) {
        const int d = wn + j*16 + l15;
#pragma unroll
        for (int r = 0; r < 4; r++) {
          const int row = m0 + wm + i*16 + quad*4 + r;
          const int b = row >> 11, l = row & (LL - 1);
          qkv[(size_t)2*BHLD + (((size_t)(b*HB + h))*DD + d)*LL + l] = f2bf(acc[i][j][r] + bv[j]);
        }
      }
    return;
  }

  // q/k: fp32 RMSNorm over d (the tile's 128 cols) + RoPE, then scatter
  float ss[4][4];
#pragma unroll
  for (int i = 0; i < 4; i++)
#pragma unroll
    for (int r = 0; r < 4; r++) {
      float s = 0.f;
#pragma unroll
      for (int j = 0; j < 4; j++) { float v = acc[i][j][r] + bv[j]; s += v*v; }
      s += __shfl_xor(s, 1, 64); s += __shfl_xor(s, 2, 64);
      s += __shfl_xor(s, 4, 64); s += __shfl_xor(s, 8, 64);
      ss[i][r] = s;   // sum over this wave's 64 cols, all 16 lanes of group hold it
    }
  __syncthreads();                    // all waves done reading As
  float* sp = (float*)As;             // [4 waves][64 rows]
  if (l15 == 0) {
#pragma unroll
    for (int i = 0; i < 4; i++)
#pragma unroll
      for (int r = 0; r < 4; r++) sp[wid*64 + i*16 + quad*4 + r] = ss[i][r];
  }
  __syncthreads();
  float rrms[4][4];
  const float qfac = 0.08838834764831845f;  // 1/sqrt(128) folded into q
#pragma unroll
  for (int i = 0; i < 4; i++)
#pragma unroll
    for (int r = 0; r < 4; r++) {
      const float tot = ss[i][r] + sp[(wid^1)*64 + i*16 + quad*4 + r];
      float rr = rsqrtf(tot * (1.0f/128.0f) + 1e-6f);
      if (t == 0) rr *= qfac;
      rrms[i][r] = rr;
    }
  const float* scp = t ? ksc : qsc;
  float scv[4];
#pragma unroll
  for (int j = 0; j < 4; j++) scv[j] = scp[wn + j*16 + l15];
#pragma unroll
  for (int i = 0; i < 4; i++)
#pragma unroll
    for (int j = 0; j < 4; j++) {
      const int d = wn + j*16 + l15;
#pragma unroll
      for (int r = 0; r < 4; r++) {
        const int row = m0 + wm + i*16 + quad*4 + r;
        const int b = row >> 11, l = row & (LL - 1);
        const float y  = (acc[i][j][r] + bv[j]) * rrms[i][r] * scv[j];
        const float yo = __shfl_xor(y, 1, 64);
        const float4 p4 = *(const float4*)&pe[((size_t)l*64 + (d >> 1)) * 4]; // {c,-s,s,c}
        const float o = (l15 & 1) ? (p4.w*y + p4.z*yo) : (p4.x*y + p4.y*yo);
        qkv[(size_t)t*BHLD + (((size_t)(b*HB + h))*LL + l)*DD + d] = f2bf(o);
      }
    }
}

// ---------------- flash attention v5 (unchanged from round 7) ----------------
// Fixed-shift softmax (|s|<=sqrt(128) since q,k RMS-normed): no running max/rescale.
// BKT=64, 64 KB LDS dbuf, 2 blocks/CU. XOR-swizzled K/V tiles, async global_load_lds.
// S^T = K.Q^T (16x16x32) -> P lands in A-operand layout for PV (16x16x16). O in regs.
#define BKT 64
__global__ __launch_bounds__(256, 2) void attn(
    const u16* __restrict__ qkv, u16* __restrict__ Oout)
{
  __shared__ __align__(16) u16 Ksh[2][BKT * DD];   // 2 x 16 KB
  __shared__ __align__(16) u16 Vsh[2][DD * BKT];   // 2 x 16 KB

  const int bh = blockIdx.x & 31, qt = blockIdx.x >> 5;   // XCD-locality swizzle
  const int wid = threadIdx.x >> 6, lane = threadIdx.x & 63;
  const int l15 = lane & 15, quad = lane >> 4;
  const int q0 = qt * 128 + wid * 32;
  const u16* qp = qkv + (size_t)bh * LL * DD;
  const u16* kp = qkv + (size_t)BHLD + (size_t)bh * LL * DD;
  const u16* vp = qkv + (size_t)2 * BHLD + (size_t)bh * DD * LL;  // V^T [D][L]

  bf16x8 qb[2][4];
#pragma unroll
  for (int qf = 0; qf < 2; qf++)
#pragma unroll
    for (int f = 0; f < 4; f++)
      qb[qf][f] = *(const bf16x8*)&qp[(size_t)(q0 + qf*16 + l15) * DD + f*32 + quad*8];

  float l_acc[2] = {0.f, 0.f};
  f32x4 oacc[2][8] = {};

  auto stage = [&](int buf, int k0) {
#pragma unroll
    for (int j = 0; j < 4; j++) {
      const int s = (wid*4 + j)*64 + lane;
      { // K: 64 rows x 16 chunks of 16B
        const int r = s >> 4, c = s & 15;
        const int lc = (c & 8) | ((c & 7) ^ (r & 7));
        gload16(&kp[(size_t)(k0 + r) * DD + lc*8], &Ksh[buf][(wid*4 + j)*512]);
      }
      { // V^T: 128 rows x 8 chunks of 16B
        const int r = s >> 3, c = s & 7;
        const int lc = c ^ (r & 7);
        gload16(&vp[(size_t)r * LL + k0 + lc*8], &Vsh[buf][(wid*4 + j)*512]);
      }
    }
  };

  stage(0, 0);
  int cur = 0;

  for (int k0 = 0; k0 < LL; k0 += BKT) {
    __syncthreads();                       // drains buf[cur] loads; frees buf[cur^1]

    // phase 1: QK
    f32x4 s[2][4] = {};
#pragma unroll
    for (int f = 0; f < 4; f++) {
      bf16x8 kf[4];
#pragma unroll
      for (int mt = 0; mt < 4; mt++) {
        const int rr = mt*16 + l15;
        const int Lc = f*4 + quad;
        const int pc = (Lc & 8) | ((Lc & 7) ^ (rr & 7));
        kf[mt] = *(const bf16x8*)&Ksh[cur][rr*DD + pc*8];
      }
#pragma unroll
      for (int qf = 0; qf < 2; qf++)
#pragma unroll
        for (int mt = 0; mt < 4; mt++)
          s[qf][mt] = __builtin_amdgcn_mfma_f32_16x16x32_bf16(kf[mt], qb[qf][f], s[qf][mt], 0, 0, 0);
    }

    // phase 2: all V frags
    s16x4 vb[4][8];
#pragma unroll
    for (int tt = 0; tt < 4; tt++)
#pragma unroll
      for (int c = 0; c < 8; c++) {
        const int rv = c*16 + l15;
        const int pc = (tt*2 + (quad >> 1)) ^ (l15 & 7);
        vb[tt][c] = *(const s16x4*)&Vsh[cur][rv*BKT + pc*8 + (quad & 1)*4];
      }

    // phase 3: next tile's async loads
    if (k0 + BKT < LL) stage(cur ^ 1, k0 + BKT);

    // phase 4: exp(s-12), l, pack
    s16x4 pa[2][4];
#pragma unroll
    for (int qf = 0; qf < 2; qf++)
#pragma unroll
      for (int mt = 0; mt < 4; mt++) {
        float p0 = __expf(s[qf][mt][0] - 12.f);
        float p1 = __expf(s[qf][mt][1] - 12.f);
        float p2 = __expf(s[qf][mt][2] - 12.f);
        float p3 = __expf(s[qf][mt][3] - 12.f);
        l_acc[qf] += (p0 + p1) + (p2 + p3);
        pa[qf][mt][0] = (short)f2bf(p0); pa[qf][mt][1] = (short)f2bf(p1);
        pa[qf][mt][2] = (short)f2bf(p2); pa[qf][mt][3] = (short)f2bf(p3);
      }

    // phase 5: PV
#pragma unroll
    for (int tt = 0; tt < 4; tt++)
#pragma unroll
      for (int qf = 0; qf < 2; qf++)
#pragma unroll
        for (int c = 0; c < 8; c++)
          oacc[qf][c] = __builtin_amdgcn_mfma_f32_16x16x16bf16_1k(pa[qf][tt], vb[tt][c], oacc[qf][c], 0, 0, 0);

    cur ^= 1;
  }

#pragma unroll
  for (int qf = 0; qf < 2; qf++) {
    l_acc[qf] += __shfl_xor(l_acc[qf], 16, 64);
    l_acc[qf] += __shfl_xor(l_acc[qf], 32, 64);
  }
  const int b = bh >> 4, h = bh & 15;
#pragma unroll
  for (int qf = 0; qf < 2; qf++) {
    float lr[4];
#pragma unroll
    for (int r = 0; r < 4; r++)
      lr[r] = 1.0f / __shfl(l_acc[qf], (quad << 4) | (quad*4 + r), 64);
#pragma unroll
    for (int c = 0; c < 8; c++)
#pragma unroll
      for (int r = 0; r < 4; r++) {
        int qrow = q0 + qf*16 + quad*4 + r;
        Oout[((size_t)(b*LL + qrow)) * N2 + h*DD + c*16 + l15] = f2bf(oacc[qf][c][r] * lr[r]);
      }
  }
}

// ---------------- launch ----------------

extern "C" void kernel_launch(void* const* d_in, const int* in_sizes, int n_in,
                              void* d_out, int out_size, void* d_ws, size_t ws_size,
                              hipStream_t stream) {
  const float* x       = (const float*)d_in[0];
  const float* pe      = (const float*)d_in[1];
  const float* qkv_w   = (const float*)d_in[2];
  const float* qkv_b   = (const float*)d_in[3];
  const float* q_scale = (const float*)d_in[4];
  const float* k_scale = (const float*)d_in[5];
  const float* proj_w  = (const float*)d_in[6];
  const float* proj_b  = (const float*)d_in[7];

  // workspace layout (bytes): needs 112 MB
  char* ws = (char*)d_ws;
  u16* xb   = (u16*)(ws + 0);           // [4096][2048] bf16   : 16 MB
  u16* w1t  = (u16*)(ws + 16777216);    // [6144][2048] bf16   : 24 MB
  u16* w2t  = (u16*)(ws + 41943040);    // [2048][2048] bf16   :  8 MB
  u16* qkv  = (u16*)(ws + 50331648);    // q,k [B,H,L,D], v [B,H,D,L] bf16 : 48 MB
  u16* attO = (u16*)(ws + 100663296);   // [4096][2048] bf16   : 16 MB

  prep<<<24576, 256, 0, stream>>>(x, xb, qkv_w, w1t, proj_w, w2t);
  gemm_bt<0><<<dim3(N1/128, MM/128), 256, 0, stream>>>(
      xb, w1t, qkv_b, (void*)qkv, pe, q_scale, k_scale, MM, N1, KK);
  attn<<<BB*HB*(LL/128), 256, 0, stream>>>(qkv, attO);
  gemm_bt<1><<<dim3(N2/128, MM/128), 256, 0, stream>>>(
      attO, w2t, proj_b, d_out, nullptr, nullptr, nullptr, MM, N2, KK);
}